// Round 5
// baseline (85.520 us; speedup 1.0000x reference)
//
#include <hip/hip_runtime.h>
#include <math.h>
#include <float.h>

#define HW      224
#define NPIX    50176      // 224*224
#define NBINS   49
#define NBC     768        // 128*6
#define NSTRIPE 7
#define STRIPEF 7168       // 32*224 floats per stripe

typedef float fx4 __attribute__((ext_vector_type(4)));

__device__ __constant__ float c_P[36] = {
  1.0f, 0.0f, 0.6f, 0.0f, -2.0f, 0.0f,
  0.0f, 1.0f, 0.6f, 0.0f,  0.0f, 0.0f,
  0.1f, 0.1f, 0.5f, 0.0f,  0.0f, 0.0f,
  0.0f, 0.0f, 0.0f, 1.0f,  0.0f, 0.0f,
  0.0f, 0.0f, 0.0f, 0.0f,  1.0f, 0.2f,
  0.0f,-0.6f,-0.6f,-0.6f,  0.6f, 1.0f
};

// ---------------------------------------------------------------------------
// K1: per-(b,c,stripe) partial sum/sumsq. 5376 blocks x 256 thr.
// Normal (caching) loads: we WANT x resident in L3 for K2's re-read.
// ---------------------------------------------------------------------------
__global__ __launch_bounds__(256)
void stats_partial_kernel(const float* __restrict__ x, float* __restrict__ part) {
  const int bid = blockIdx.x;                 // bc*7 + stripe
  const int t = threadIdx.x;
  const float4* __restrict__ p = (const float4*)(x + (size_t)bid * STRIPEF);

  float s = 0.f, ss = 0.f;
  #pragma unroll
  for (int k = 0; k < 7; ++k) {
    float4 u = p[t + k * 256];
    s += (u.x + u.y) + (u.z + u.w);
    ss = fmaf(u.x, u.x, fmaf(u.y, u.y, fmaf(u.z, u.z, fmaf(u.w, u.w, ss))));
  }
  #pragma unroll
  for (int off = 32; off; off >>= 1) {
    s  += __shfl_down(s, off);
    ss += __shfl_down(ss, off);
  }
  __shared__ float red[8];
  const int lane = t & 63, w = t >> 6;
  if (lane == 0) { red[w] = s; red[4 + w] = ss; }
  __syncthreads();
  if (t == 0) part[bid * 2]     = red[0] + red[1] + red[2] + red[3];
  if (t == 1) part[bid * 2 + 1] = red[4] + red[5] + red[6] + red[7];
}

// ---------------------------------------------------------------------------
// K2: finish stats, sigmoid, 32x32 window means for one stripe (7 windows).
// ---------------------------------------------------------------------------
__global__ __launch_bounds__(256)
void pool_kernel(const float* __restrict__ x, const float* __restrict__ part,
                 float* __restrict__ pooled) {
  const int bid = blockIdx.x;                 // bc*7 + binrow
  const int bc = bid / 7;
  const int binrow = bid - bc * 7;
  const int t = threadIdx.x;

  __shared__ float stat[2];
  if (t < 2) {
    float a = 0.f;
    #pragma unroll
    for (int i = 0; i < 7; ++i) a += part[(bc * 7 + i) * 2 + t];
    stat[t] = a;
  }
  __syncthreads();
  const float mean  = stat[0] * (1.f / (float)NPIX);
  const float var   = (stat[1] - stat[0] * mean) * (1.f / (float)(NPIX - 1));
  const float scale = 2.0f / (sqrtf(var) + 1e-5f);   // /std/TAU, TAU=0.5

  const int r = t >> 3, c = t & 7;
  const float4* __restrict__ p = (const float4*)(x + (size_t)bid * STRIPEF);

  float sv[7];
  #pragma unroll
  for (int j = 0; j < 7; ++j) {
    float4 u = p[r * 56 + j * 8 + c];
    sv[j] = 1.f / (1.f + __expf((mean - u.x) * scale))
          + 1.f / (1.f + __expf((mean - u.y) * scale))
          + 1.f / (1.f + __expf((mean - u.z) * scale))
          + 1.f / (1.f + __expf((mean - u.w) * scale));
  }
  #pragma unroll
  for (int j = 0; j < 7; ++j) {
    float a = sv[j];
    #pragma unroll
    for (int off = 32; off; off >>= 1) a += __shfl_down(a, off);
    sv[j] = a;
  }
  __shared__ float red[4][7];
  const int lane = t & 63, w = t >> 6;
  if (lane == 0) {
    #pragma unroll
    for (int j = 0; j < 7; ++j) red[w][j] = sv[j];
  }
  __syncthreads();
  if (t < 7)
    pooled[bc * NBINS + binrow * 7 + t] =
        (red[0][t] + red[1][t] + red[2][t] + red[3][t]) * (1.f / 1024.f);
}

// ---------------------------------------------------------------------------
// K3: salient + graph message passing (separable D) + features + upsample.
// out written with NON-TEMPORAL stores: write-once data must not occupy L3,
// so x stays L3-resident for the next kernels/replays.
// ---------------------------------------------------------------------------
__global__ __launch_bounds__(256)
void graph_upsample_kernel(const float* __restrict__ pooled,
                           const float* __restrict__ P_delta,
                           float* __restrict__ feat, float* __restrict__ out) {
  const int bc = blockIdx.x;
  const int b = bc / 6, d = bc % 6;
  const int t = threadIdx.x;

  __shared__ float pl[6][NBINS];
  __shared__ float chm[6];
  __shared__ float ps[6], w7[7];
  __shared__ float tm[7][7], hh[7][7], g[7][7];
  __shared__ float gy[HW][7];

  for (int i = t; i < 6 * NBINS; i += 256)
    pl[i / NBINS][i % NBINS] = pooled[(size_t)b * 6 * NBINS + i];
  if (t < 6) ps[t] = c_P[t * 6 + d] + 0.2f * tanhf(P_delta[t * 6 + d]);
  if (t >= 64 && t < 71) {
    const int k = t - 64;
    w7[k] = expf(-(float)(k * k) * (1.0f / 1.28f));   // 2*sigma^2 = 1.28
  }
  __syncthreads();

  if (t < 6) {
    float a = 0.f;
    #pragma unroll
    for (int i = 0; i < NBINS; ++i) a += pl[t][i];
    chm[t] = a * (1.f / 49.f);
  }
  __syncthreads();
  for (int i = t; i < 6 * NBINS; i += 256) {
    const int c = i / NBINS, s = i % NBINS;
    const float sgc = (c == 1 || c == 3) ? -1.f : 1.f;
    float v = sgc * (pl[c][s] - chm[c]);
    pl[c][s] = v > 0.f ? v : 0.f;
  }
  __syncthreads();

  if (t < NBINS) {
    float a = 0.f;
    #pragma unroll
    for (int c = 0; c < 6; ++c) a += pl[c][t] * ps[c];
    tm[t / 7][t % 7] = a;
  }
  __syncthreads();
  if (t < NBINS) {
    const int ys = t / 7, xt = t % 7;
    float a = 0.f;
    #pragma unroll
    for (int xs = 0; xs < 7; ++xs) a += tm[ys][xs] * w7[xs > xt ? xs - xt : xt - xs];
    hh[ys][xt] = a;
  }
  __syncthreads();
  const float sg = (d == 1 || d == 3) ? -1.f : 1.f;
  if (t < NBINS) {
    const int yt = t / 7, xt = t % 7;
    float a = 0.f;
    #pragma unroll
    for (int ys = 0; ys < 7; ++ys) a += hh[ys][xt] * w7[ys > yt ? ys - yt : yt - ys];
    a = a > 0.f ? a : 0.f;    // relu
    g[yt][xt] = a * sg;       // sign flip
  }
  __syncthreads();

  if (t < 64) {
    const float vv = (t < NBINS) ? g[t / 7][t % 7] : 0.f;
    float vs  = (t < NBINS) ? vv : 0.f;
    float vmx = (t < NBINS) ? vv : -FLT_MAX;
    float vmn = (t < NBINS) ? vv : FLT_MAX;
    #pragma unroll
    for (int off = 32; off; off >>= 1) {
      vs += __shfl_down(vs, off);
      vmx = fmaxf(vmx, __shfl_down(vmx, off));
      vmn = fminf(vmn, __shfl_down(vmn, off));
    }
    if (t == 0) {
      feat[b * 18 + d]      = vs * (1.f / 49.f);
      feat[b * 18 + 6 + d]  = vmx;
      feat[b * 18 + 12 + d] = vmn;
    }
  }

  for (int i = t; i < HW * 7; i += 256) {
    const int row = i / 7, xs = i % 7;
    const int y0 = (row >= 16) ? ((row - 16) >> 5) : -1;
    const float fy = (row - 15.5f) * 0.03125f - (float)y0;
    const int y0c = y0 < 0 ? 0 : y0;
    const int y1c = (y0 + 1 > 6) ? 6 : (y0 + 1);
    gy[row][xs] = (1.f - fy) * g[y0c][xs] + fy * g[y1c][xs];
  }
  __syncthreads();

  fx4* __restrict__ op = (fx4*)(out + (size_t)bc * NPIX);
  #pragma unroll
  for (int k = 0; k < 49; ++k) {
    const int i = t + k * 256;           // 0..12543
    const int row = i / 56, c4 = i % 56;
    const float* gr = &gy[row][0];
    fx4 r;
    #pragma unroll
    for (int jj = 0; jj < 4; ++jj) {
      const int xx = c4 * 4 + jj;
      const int x0 = (xx >= 16) ? ((xx - 16) >> 5) : -1;
      const float fx = (xx - 15.5f) * 0.03125f - (float)x0;
      const int x0c = x0 < 0 ? 0 : x0;
      const int x1c = (x0 + 1 > 6) ? 6 : (x0 + 1);
      r[jj] = (1.f - fx) * gr[x0c] + fx * gr[x1c];
    }
    __builtin_nontemporal_store(r, &op[i]);
  }
}

// ---------------------------------------------------------------------------
extern "C" void kernel_launch(void* const* d_in, const int* in_sizes, int n_in,
                              void* d_out, int out_size, void* d_ws, size_t ws_size,
                              hipStream_t stream) {
  const float* x       = (const float*)d_in[0];
  const float* P_delta = (const float*)d_in[1];
  float* outp = (float*)d_out;

  float* part   = (float*)d_ws;                    // 5376*2 floats
  float* pooled = part + NBC * NSTRIPE * 2;        // 768*49 floats

  float* feat = outp;                              // (128,18)
  float* ups  = outp + 128 * 18;                   // (128,6,224,224)

  stats_partial_kernel<<<NBC * NSTRIPE, 256, 0, stream>>>(x, part);
  pool_kernel<<<NBC * NSTRIPE, 256, 0, stream>>>(x, part, pooled);
  graph_upsample_kernel<<<NBC, 256, 0, stream>>>(pooled, P_delta, feat, ups);
}